// Round 3
// baseline (526.093 us; speedup 1.0000x reference)
//
#include <hip/hip_runtime.h>

// SpanMaskGenerator: B=256, S=131072, 4 spans/batch.
// Outputs (concatenated int32): context_mask [B,S], target_mask [B,S],
// padded_positions [B,S] (masked positions ascending, sentinel = S).
//
// Union of 4 start-sorted spans = <=4 disjoint ascending segments
// [max(ss[i],M_{i-1}), max(ee[i],M_{i-1})) with M = running max of ends.
// padded_positions is a closed-form per-index lookup -> pure streaming map.
// R3: ITEMS=16 + nontemporal stores via clang ext_vector_type (HIP int4 is a
// class and is rejected by __builtin_nontemporal_store).

constexpr int S_LEN = 131072;
constexpr int NBLK  = 4;
constexpr int TPB   = 256;
constexpr int ITEMS = 16;

typedef int int4v __attribute__((ext_vector_type(4)));

__global__ __launch_bounds__(TPB) void span_mask_kernel(
    const float* __restrict__ scales_u,
    const float* __restrict__ starts_u,
    int* __restrict__ out,
    int batch)
{
    const int b = blockIdx.y;

    // ---- per-batch span computation (uniform across threads; cheap) ----
    // Exact f32 replication of the reference: separate mul/add (no fma
    // contraction), truncating int casts.
    int ss[NBLK], ee[NBLK];
#pragma unroll
    for (int t = 0; t < NBLK; ++t) {
        float u  = scales_u[b * NBLK + t];
        float r  = starts_u[b * NBLK + t];
        float sc = __fadd_rn(0.15f, __fmul_rn(u, 0.05f));      // U(0.15,0.2)
        int len  = (int)__fmul_rn(sc, 131072.0f);              // trunc
        if (len < 1) len = 1;
        int mx   = S_LEN - len; if (mx < 0) mx = 0;
        int st   = (int)__fmul_rn(r, __fadd_rn((float)mx, 1.0f)); // trunc
        int en   = st + len; if (en > S_LEN) en = S_LEN;
        ss[t] = st; ee[t] = en;
    }

    // ---- sort 4 spans by start (sorting network, static indices only) ----
#define CSWAP(i, j)                                                        \
    if (ss[i] > ss[j]) {                                                   \
        int t0 = ss[i]; ss[i] = ss[j]; ss[j] = t0;                         \
        int t1 = ee[i]; ee[i] = ee[j]; ee[j] = t1;                         \
    }
    CSWAP(0, 1) CSWAP(2, 3) CSWAP(0, 2) CSWAP(1, 3) CSWAP(1, 2)
#undef CSWAP

    // ---- marginal-contribution segments (disjoint, ascending) ----
    const int L0 = ss[0],          R0 = ee[0];
    const int L1 = max(ss[1], R0), R1 = max(ee[1], R0);
    const int L2 = max(ss[2], R1), R2 = max(ee[2], R1);
    const int L3 = max(ss[3], R2), R3 = max(ee[3], R2);
    const int c1 = R0 - L0;                 // cumulative masked counts
    const int c2 = c1 + (R1 - L1);
    const int c3 = c2 + (R2 - L2);
    const int total = c3 + (R3 - L3);

    const size_t BS   = (size_t)batch * S_LEN;
    const size_t base = (size_t)b * S_LEN;
    int* __restrict__ ctx = out + base;            // context_mask
    int* __restrict__ tgt = out + BS + base;       // target_mask
    int* __restrict__ pad = out + 2 * BS + base;   // padded_positions

    const int p0 = (blockIdx.x * TPB + threadIdx.x) * ITEMS;

    int tv[ITEMS], cv[ITEMS], pv[ITEMS];
#pragma unroll
    for (int i = 0; i < ITEMS; ++i) {
        const int s = p0 + i;
        const int cov =
            ((s >= ss[0]) & (s < ee[0])) | ((s >= ss[1]) & (s < ee[1])) |
            ((s >= ss[2]) & (s < ee[2])) | ((s >= ss[3]) & (s < ee[3]));
        tv[i] = cov;
        cv[i] = cov ^ 1;
        // padded_positions[k]: k-th masked position, else sentinel S_LEN.
        int v;
        if      (s >= total) v = S_LEN;
        else if (s >= c3)    v = L3 + (s - c3);
        else if (s >= c2)    v = L2 + (s - c2);
        else if (s >= c1)    v = L1 + (s - c1);
        else                 v = L0 + s;
        pv[i] = v;
    }

#pragma unroll
    for (int q = 0; q < ITEMS / 4; ++q) {
        int4v c4 = { cv[4*q], cv[4*q+1], cv[4*q+2], cv[4*q+3] };
        int4v t4 = { tv[4*q], tv[4*q+1], tv[4*q+2], tv[4*q+3] };
        int4v p4 = { pv[4*q], pv[4*q+1], pv[4*q+2], pv[4*q+3] };
        __builtin_nontemporal_store(c4, reinterpret_cast<int4v*>(ctx + p0) + q);
        __builtin_nontemporal_store(t4, reinterpret_cast<int4v*>(tgt + p0) + q);
        __builtin_nontemporal_store(p4, reinterpret_cast<int4v*>(pad + p0) + q);
    }
}

extern "C" void kernel_launch(void* const* d_in, const int* in_sizes, int n_in,
                              void* d_out, int out_size, void* d_ws, size_t ws_size,
                              hipStream_t stream)
{
    const float* scales_u = (const float*)d_in[0];
    const float* starts_u = (const float*)d_in[1];
    // d_in[2]/d_in[3] are batch_size=256 / seq_len=131072 scalars (fixed).
    const int batch = 256;
    dim3 grid(S_LEN / (TPB * ITEMS), batch);   // (32, 256)
    span_mask_kernel<<<grid, dim3(TPB), 0, stream>>>(
        scales_u, starts_u, (int*)d_out, batch);
}

// Round 4
// 81.522 us; speedup vs baseline: 6.4534x; 6.4534x over previous
//
#include <hip/hip_runtime.h>

// SpanMaskGenerator: B=256, S=131072, 4 spans/batch.
// Outputs (concatenated int32): context_mask [B,S], target_mask [B,S],
// padded_positions [B,S] (masked positions ascending, sentinel = S).
//
// Union of 4 start-sorted spans = <=4 disjoint ascending segments
// [max(ss[i],M_{i-1}), max(ee[i],M_{i-1})) with M = running max of ends.
// padded_positions is a closed-form per-index lookup -> pure streaming map.
//
// R4: WAVE-CONTIGUOUS nt stores. R3's per-thread-contiguous layout (64B lane
// stride) + nt = partial-line HBM writes -> 2.8x write amplification
// (WRITE_SIZE 1.14GB vs 402MB ideal). nt bypasses L2 write-combining, so each
// wave store must itself cover full lines: lane t stores int4 at
// base + q*1024B + t*16B -> 1024B contiguous per wave store.

constexpr int S_LEN = 131072;
constexpr int NBLK  = 4;
constexpr int TPB   = 256;
constexpr int ITEMS = 16;              // elements per thread (4 int4 chunks)

typedef int int4v __attribute__((ext_vector_type(4)));

__global__ __launch_bounds__(TPB) void span_mask_kernel(
    const float* __restrict__ scales_u,
    const float* __restrict__ starts_u,
    int* __restrict__ out,
    int batch)
{
    const int b = blockIdx.y;

    // ---- per-batch span computation (uniform across threads; cheap) ----
    // Exact f32 replication of the reference: separate mul/add (no fma
    // contraction), truncating int casts.
    int ss[NBLK], ee[NBLK];
#pragma unroll
    for (int t = 0; t < NBLK; ++t) {
        float u  = scales_u[b * NBLK + t];
        float r  = starts_u[b * NBLK + t];
        float sc = __fadd_rn(0.15f, __fmul_rn(u, 0.05f));      // U(0.15,0.2)
        int len  = (int)__fmul_rn(sc, 131072.0f);              // trunc
        if (len < 1) len = 1;
        int mx   = S_LEN - len; if (mx < 0) mx = 0;
        int st   = (int)__fmul_rn(r, __fadd_rn((float)mx, 1.0f)); // trunc
        int en   = st + len; if (en > S_LEN) en = S_LEN;
        ss[t] = st; ee[t] = en;
    }

    // ---- sort 4 spans by start (sorting network, static indices only) ----
#define CSWAP(i, j)                                                        \
    if (ss[i] > ss[j]) {                                                   \
        int t0 = ss[i]; ss[i] = ss[j]; ss[j] = t0;                         \
        int t1 = ee[i]; ee[i] = ee[j]; ee[j] = t1;                         \
    }
    CSWAP(0, 1) CSWAP(2, 3) CSWAP(0, 2) CSWAP(1, 3) CSWAP(1, 2)
#undef CSWAP

    // ---- marginal-contribution segments (disjoint, ascending) ----
    const int L0 = ss[0],          R0 = ee[0];
    const int L1 = max(ss[1], R0), R1 = max(ee[1], R0);
    const int L2 = max(ss[2], R1), R2 = max(ee[2], R1);
    const int L3 = max(ss[3], R2), R3 = max(ee[3], R2);
    const int c1 = R0 - L0;                 // cumulative masked counts
    const int c2 = c1 + (R1 - L1);
    const int c3 = c2 + (R2 - L2);
    const int total = c3 + (R3 - L3);

    const size_t BS   = (size_t)batch * S_LEN;
    const size_t base = (size_t)b * S_LEN;
    int* __restrict__ ctx = out + base;            // context_mask
    int* __restrict__ tgt = out + BS + base;       // target_mask
    int* __restrict__ pad = out + 2 * BS + base;   // padded_positions

    const int blockStart = blockIdx.x * (TPB * ITEMS);

#pragma unroll
    for (int q = 0; q < ITEMS / 4; ++q) {
        // wave-contiguous: consecutive lanes -> consecutive int4s
        const int s0 = blockStart + q * (TPB * 4) + threadIdx.x * 4;
        int cv[4], tv[4], pv[4];
#pragma unroll
        for (int j = 0; j < 4; ++j) {
            const int s = s0 + j;
            const int cov =
                ((s >= ss[0]) & (s < ee[0])) | ((s >= ss[1]) & (s < ee[1])) |
                ((s >= ss[2]) & (s < ee[2])) | ((s >= ss[3]) & (s < ee[3]));
            tv[j] = cov;
            cv[j] = cov ^ 1;
            // padded_positions[k]: k-th masked position, else sentinel S_LEN.
            int v;
            if      (s >= total) v = S_LEN;
            else if (s >= c3)    v = L3 + (s - c3);
            else if (s >= c2)    v = L2 + (s - c2);
            else if (s >= c1)    v = L1 + (s - c1);
            else                 v = L0 + s;
            pv[j] = v;
        }
        int4v c4 = { cv[0], cv[1], cv[2], cv[3] };
        int4v t4 = { tv[0], tv[1], tv[2], tv[3] };
        int4v p4 = { pv[0], pv[1], pv[2], pv[3] };
        __builtin_nontemporal_store(c4, reinterpret_cast<int4v*>(ctx + s0));
        __builtin_nontemporal_store(t4, reinterpret_cast<int4v*>(tgt + s0));
        __builtin_nontemporal_store(p4, reinterpret_cast<int4v*>(pad + s0));
    }
}

extern "C" void kernel_launch(void* const* d_in, const int* in_sizes, int n_in,
                              void* d_out, int out_size, void* d_ws, size_t ws_size,
                              hipStream_t stream)
{
    const float* scales_u = (const float*)d_in[0];
    const float* starts_u = (const float*)d_in[1];
    // d_in[2]/d_in[3] are batch_size=256 / seq_len=131072 scalars (fixed).
    const int batch = 256;
    dim3 grid(S_LEN / (TPB * ITEMS), batch);   // (32, 256)
    span_mask_kernel<<<grid, dim3(TPB), 0, stream>>>(
        scales_u, starts_u, (int*)d_out, batch);
}

// Round 5
// 78.749 us; speedup vs baseline: 6.6806x; 1.0352x over previous
//
#include <hip/hip_runtime.h>

// SpanMaskGenerator: B=256, S=131072, 4 spans/batch.
// Outputs (concatenated int32): context_mask [B,S], target_mask [B,S],
// padded_positions [B,S] (masked positions ascending, sentinel = S).
//
// Union of 4 start-sorted spans = <=4 disjoint ascending segments
// [max(ss[i],M_{i-1}), max(ee[i],M_{i-1})) with M = running max of ends.
// padded_positions is a closed-form per-index lookup -> pure streaming map.
//
// R5: wave-contiguous PLAIN stores. History:
//   R1: plain stores, 32B lane stride        -> 68.8 us (5.85 TB/s)
//   R3: nt stores, 64B lane stride           -> 526 us (2.8x write amp: nt
//       bypasses L2 write-combining, partial-line HBM writes)
//   R4: nt stores, wave-contiguous           -> 81.5 us (4.94 TB/s: nt path
//       itself is slower than L2-buffered streaming writes)
// The harness fill kernel (plain, wave-contiguous) sustains 6.9 TB/s -> copy
// that pattern: L2-buffered writes + 1024B-contiguous wave stores.

constexpr int S_LEN = 131072;
constexpr int NBLK  = 4;
constexpr int TPB   = 256;
constexpr int ITEMS = 16;              // elements per thread (4 int4 chunks)

typedef int int4v __attribute__((ext_vector_type(4)));

__global__ __launch_bounds__(TPB) void span_mask_kernel(
    const float* __restrict__ scales_u,
    const float* __restrict__ starts_u,
    int* __restrict__ out,
    int batch)
{
    const int b = blockIdx.y;

    // ---- per-batch span computation (uniform across threads; cheap) ----
    // Exact f32 replication of the reference: separate mul/add (no fma
    // contraction), truncating int casts.
    int ss[NBLK], ee[NBLK];
#pragma unroll
    for (int t = 0; t < NBLK; ++t) {
        float u  = scales_u[b * NBLK + t];
        float r  = starts_u[b * NBLK + t];
        float sc = __fadd_rn(0.15f, __fmul_rn(u, 0.05f));      // U(0.15,0.2)
        int len  = (int)__fmul_rn(sc, 131072.0f);              // trunc
        if (len < 1) len = 1;
        int mx   = S_LEN - len; if (mx < 0) mx = 0;
        int st   = (int)__fmul_rn(r, __fadd_rn((float)mx, 1.0f)); // trunc
        int en   = st + len; if (en > S_LEN) en = S_LEN;
        ss[t] = st; ee[t] = en;
    }

    // ---- sort 4 spans by start (sorting network, static indices only) ----
#define CSWAP(i, j)                                                        \
    if (ss[i] > ss[j]) {                                                   \
        int t0 = ss[i]; ss[i] = ss[j]; ss[j] = t0;                         \
        int t1 = ee[i]; ee[i] = ee[j]; ee[j] = t1;                         \
    }
    CSWAP(0, 1) CSWAP(2, 3) CSWAP(0, 2) CSWAP(1, 3) CSWAP(1, 2)
#undef CSWAP

    // ---- marginal-contribution segments (disjoint, ascending) ----
    const int L0 = ss[0],          R0 = ee[0];
    const int L1 = max(ss[1], R0), R1 = max(ee[1], R0);
    const int L2 = max(ss[2], R1), R2 = max(ee[2], R1);
    const int L3 = max(ss[3], R2), R3 = max(ee[3], R2);
    const int c1 = R0 - L0;                 // cumulative masked counts
    const int c2 = c1 + (R1 - L1);
    const int c3 = c2 + (R2 - L2);
    const int total = c3 + (R3 - L3);

    const size_t BS   = (size_t)batch * S_LEN;
    const size_t base = (size_t)b * S_LEN;
    int* __restrict__ ctx = out + base;            // context_mask
    int* __restrict__ tgt = out + BS + base;       // target_mask
    int* __restrict__ pad = out + 2 * BS + base;   // padded_positions

    const int blockStart = blockIdx.x * (TPB * ITEMS);

#pragma unroll
    for (int q = 0; q < ITEMS / 4; ++q) {
        // wave-contiguous: consecutive lanes -> consecutive int4s
        const int s0 = blockStart + q * (TPB * 4) + threadIdx.x * 4;
        int cv[4], tv[4], pv[4];
#pragma unroll
        for (int j = 0; j < 4; ++j) {
            const int s = s0 + j;
            const int cov =
                ((s >= ss[0]) & (s < ee[0])) | ((s >= ss[1]) & (s < ee[1])) |
                ((s >= ss[2]) & (s < ee[2])) | ((s >= ss[3]) & (s < ee[3]));
            tv[j] = cov;
            cv[j] = cov ^ 1;
            // padded_positions[k]: k-th masked position, else sentinel S_LEN.
            int v;
            if      (s >= total) v = S_LEN;
            else if (s >= c3)    v = L3 + (s - c3);
            else if (s >= c2)    v = L2 + (s - c2);
            else if (s >= c1)    v = L1 + (s - c1);
            else                 v = L0 + s;
            pv[j] = v;
        }
        int4v c4 = { cv[0], cv[1], cv[2], cv[3] };
        int4v t4 = { tv[0], tv[1], tv[2], tv[3] };
        int4v p4 = { pv[0], pv[1], pv[2], pv[3] };
        *(reinterpret_cast<int4v*>(ctx + s0)) = c4;
        *(reinterpret_cast<int4v*>(tgt + s0)) = t4;
        *(reinterpret_cast<int4v*>(pad + s0)) = p4;
    }
}

extern "C" void kernel_launch(void* const* d_in, const int* in_sizes, int n_in,
                              void* d_out, int out_size, void* d_ws, size_t ws_size,
                              hipStream_t stream)
{
    const float* scales_u = (const float*)d_in[0];
    const float* starts_u = (const float*)d_in[1];
    // d_in[2]/d_in[3] are batch_size=256 / seq_len=131072 scalars (fixed).
    const int batch = 256;
    dim3 grid(S_LEN / (TPB * ITEMS), batch);   // (32, 256)
    span_mask_kernel<<<grid, dim3(TPB), 0, stream>>>(
        scales_u, starts_u, (int*)d_out, batch);
}